// Round 6
// baseline (860.618 us; speedup 1.0000x reference)
//
#include <hip/hip_runtime.h>
#include <stdint.h>

// Experts FFN: E experts, C tokens/expert, D model, F ff
#define E_ 8
#define C_ 4096
#define D_ 1024
#define F_ 4096

typedef __attribute__((ext_vector_type(8))) short bf16x8;
typedef __attribute__((ext_vector_type(4))) float f32x4;
typedef __attribute__((ext_vector_type(8))) unsigned short u16x8;
typedef __attribute__((ext_vector_type(4))) unsigned short u16x4;

__device__ __forceinline__ unsigned short f2bf(float x) {
  union { float f; uint32_t u; } v; v.f = x;
  uint32_t r = v.u + 0x7FFFu + ((v.u >> 16) & 1u);  // RNE
  return (unsigned short)(r >> 16);
}

// JAX gelu (approximate=True)
__device__ __forceinline__ float gelu_f(float x) {
  float x3 = x * x * x;
  float u = 0.7978845608028654f * __builtin_fmaf(0.044715f, x3, x);
  float t = __expf(2.0f * u);
  float th = 1.0f - 2.0f / (t + 1.0f);
  return 0.5f * x * (1.0f + th);
}

// ============================================================================
// Packed operand format (per 256-row panel, per 64-k tile; 32KB blocks):
//   elem offset = h*8192 + c*1024 + r7*8 + e
//   (h = row>>7 within panel, c = (k&63)>>3, r7 = row&127, e = k&7)
// Staging a tile = 4+4 contiguous 8KB global_load_lds (perfect coalescing).
// Frag ds_read at c*2048B + r7*16B: lanes 0-7 hit 16B-consecutive addresses
// (one full bank sweep per b128 phase) -> conflict-free. No swizzle anywhere.
// ============================================================================

// ---- pack_rm: fp32 [R][K] row-major -> packed bf16 ----
__global__ __launch_bounds__(256) void pack_rm_kernel(
    const float* __restrict__ in, unsigned short* __restrict__ out,
    int R, int K) {
  const int p = blockIdx.x, t = blockIdx.y, ge = blockIdx.z;
  const float* src = in + (size_t)ge * R * K + (size_t)(p * 256) * K + t * 64;
  unsigned short* dst =
      out + ((size_t)(ge * (R >> 8) + p) * (K >> 6) + t) * 16384;
  __shared__ unsigned short sm[256 * 72];  // row stride 144B (16B-aligned)
  const int tid = threadIdx.x;
  const int rb = tid >> 4, k4 = (tid & 15) * 4;
#pragma unroll
  for (int i = 0; i < 16; ++i) {
    int r = rb + i * 16;
    float4 v = *(const float4*)(src + (size_t)r * K + k4);
    u16x4 o;
    o[0] = f2bf(v.x); o[1] = f2bf(v.y); o[2] = f2bf(v.z); o[3] = f2bf(v.w);
    *(u16x4*)&sm[r * 72 + k4] = o;
  }
  __syncthreads();
#pragma unroll
  for (int w = 0; w < 8; ++w) {
    int o = tid * 8 + w * 2048;
    int h = o >> 13, c = (o >> 10) & 7, r7 = (o >> 3) & 127;
    int row = h * 128 + r7;
    u16x8 v = *(const u16x8*)&sm[row * 72 + c * 8];
    *(u16x8*)(dst + o) = v;
  }
}

// ---- pack_tr: fp32 [K][N] -> packed bf16 of transpose [N][K] ----
__global__ __launch_bounds__(256) void pack_tr_kernel(
    const float* __restrict__ in, unsigned short* __restrict__ out,
    int K, int N) {
  const int pn = blockIdx.x, tk = blockIdx.y, ge = blockIdx.z;
  const float* src = in + (size_t)ge * K * N + (size_t)(tk * 64) * N + pn * 256;
  unsigned short* dst =
      out + ((size_t)(ge * (N >> 8) + pn) * (K >> 6) + tk) * 16384;
  __shared__ unsigned short sm[64 * 260];  // [k][n], row stride 520B
  const int tid = threadIdx.x;
  const int kb = tid >> 6, n4 = (tid & 63) * 4;
#pragma unroll
  for (int i = 0; i < 16; ++i) {
    int kk = kb + i * 4;
    float4 v = *(const float4*)(src + (size_t)kk * N + n4);
    u16x4 o;
    o[0] = f2bf(v.x); o[1] = f2bf(v.y); o[2] = f2bf(v.z); o[3] = f2bf(v.w);
    *(u16x4*)&sm[kk * 260 + n4] = o;
  }
  __syncthreads();
#pragma unroll
  for (int w = 0; w < 8; ++w) {
    int o = tid * 8 + w * 2048;
    int h = o >> 13, c = (o >> 10) & 7, r7 = (o >> 3) & 127;
    int n = h * 128 + r7;
    u16x8 v;
#pragma unroll
    for (int e = 0; e < 8; ++e) v[e] = sm[(c * 8 + e) * 260 + n];
    *(u16x8*)(dst + o) = v;
  }
}

// ---- async global->LDS ----
typedef const __attribute__((address_space(1))) uint32_t* gas1_ptr;
typedef __attribute__((address_space(3))) uint32_t* las3_ptr;

__device__ __forceinline__ void async16(const void* g, void* l) {
  __builtin_amdgcn_global_load_lds((gas1_ptr)(uintptr_t)g, (las3_ptr)(uintptr_t)l,
                                   16, 0, 0);
}

// ============================================================================
// 256x256 4-phase bf16 GEMM on packed operands.
// 512 thr = 8 waves (2M x 4N), per-wave 128x64, BK=64, 128KiB LDS 2-dbuf.
// Per K-tile: P1{stage full t+1 tile (8x8KB linear) + read bY + MFMA(0,0)},
// P2{read aO + MFMA(0,1)}, P3{vmcnt(0) 2-phase-old + read aE@next + MFMA(1,0)},
// P4{read bZ@next + MFMA(1,1)}. lgkmcnt(0) at every phase entry (reads are
// one phase ahead); 8 barriers/K-tile.
// MODE 0: fp32 out row-major via LDS repack (coalesced). MODE 1: bf16
// gelu out in PACKED layout (feeds GEMM2's A staging directly).
// ============================================================================

#define PRE_LG() do { \
    __builtin_amdgcn_sched_barrier(0); \
    __builtin_amdgcn_s_barrier(); \
    asm volatile("s_waitcnt lgkmcnt(0)" ::: "memory"); \
    __builtin_amdgcn_sched_barrier(0); \
    __builtin_amdgcn_s_setprio(1); \
  } while (0)

#define PRE_VM() do { \
    __builtin_amdgcn_sched_barrier(0); \
    asm volatile("s_waitcnt vmcnt(0)" ::: "memory"); \
    __builtin_amdgcn_s_barrier(); \
    asm volatile("s_waitcnt lgkmcnt(0)" ::: "memory"); \
    __builtin_amdgcn_sched_barrier(0); \
    __builtin_amdgcn_s_setprio(1); \
  } while (0)

#define POST() do { \
    __builtin_amdgcn_s_setprio(0); \
    __builtin_amdgcn_sched_barrier(0); \
    __builtin_amdgcn_s_barrier(); \
    __builtin_amdgcn_sched_barrier(0); \
  } while (0)

template <int MODE>
__global__ __launch_bounds__(512, 2) void gemm256_kernel(
    const unsigned short* __restrict__ A,  // packed [panels][NT][32KB]
    const unsigned short* __restrict__ B,  // packed [panels][NT][32KB]
    const float* __restrict__ bias,        // [N]
    void* __restrict__ Cout,
    int K, int N, int numM, int numN,
    size_t aStride, size_t bStride, size_t cStride, int biasStride) {
  __shared__ char lds[131072];
  char* ldsp = (char*)lds;

  const int NT = K >> 6;

  // bijective XCD swizzle (m204)
  int lin = blockIdx.x;
  int nwg = gridDim.x;
  int qq = nwg >> 3, rr8 = nwg & 7;
  int xcd = lin & 7, idx = lin >> 3;
  int wg = (xcd < rr8 ? xcd * (qq + 1) : rr8 * (qq + 1) + (xcd - rr8) * qq) + idx;
  int per = numM * numN;
  int e = wg / per;
  int rem = wg - e * per;
  int tm = rem % numM, tn = rem / numM;

  const int rowTile = tm << 8;
  const int colTile = tn << 8;

  const int tid = threadIdx.x;
  const int lane = tid & 63;
  const int w = tid >> 6;
  const int wm = w & 1, wn = w >> 1;
  const int l15 = lane & 15, q = lane >> 4;

  // ---- staging bases: fully linear contiguous 32KB tile blocks ----
  const char* Ag = (const char*)(A + (size_t)e * aStride) +
                   (size_t)tm * NT * 32768 + tid * 16;
  const char* Bg = (const char*)(B + (size_t)e * bStride) +
                   (size_t)tn * NT * 32768 + tid * 16;
  char* ldT = ldsp + tid * 16;

#define STAGE_ALL(bb, kt) do { \
    const char* as_ = Ag + (size_t)(kt) * 32768; \
    const char* bs_ = Bg + (size_t)(kt) * 32768; \
    char* ld_ = ldT + (bb) * 65536; \
    async16(as_, ld_);                      async16(as_ + 8192, ld_ + 8192); \
    async16(as_ + 16384, ld_ + 16384);      async16(as_ + 24576, ld_ + 24576); \
    async16(bs_, ld_ + 32768);              async16(bs_ + 8192, ld_ + 40960); \
    async16(bs_ + 16384, ld_ + 49152);      async16(bs_ + 24576, ld_ + 57344); \
  } while (0)

  // ---- LDS frag read bases (packed layout: h*16384 + c*2048 + r7*16) ----
  const int aRd = wm * 16384 + q * 2048 + l15 * 16;
  const int bRd = 32768 + (wn >> 1) * 16384 + q * 2048 +
                  ((wn & 1) * 64 + l15) * 16;

  bf16x8 aE[4][2], aO[4][2], bZ[2][2], bY[2][2];
  f32x4 acc[8][4];
#pragma unroll
  for (int m = 0; m < 8; ++m)
#pragma unroll
    for (int n = 0; n < 4; ++n) acc[m][n] = {0.f, 0.f, 0.f, 0.f};

#define READ_A(dst, bb, mh) do { \
    _Pragma("unroll") for (int m4 = 0; m4 < 4; ++m4) \
    _Pragma("unroll") for (int ks = 0; ks < 2; ++ks) \
      dst[m4][ks] = *(const bf16x8*)(ldsp + (bb) * 65536 + aRd + ks * 8192 + \
                                     (mh) * 1024 + m4 * 256); \
  } while (0)

#define READ_B(dst, bb, nh) do { \
    _Pragma("unroll") for (int n2 = 0; n2 < 2; ++n2) \
    _Pragma("unroll") for (int ks = 0; ks < 2; ++ks) \
      dst[n2][ks] = *(const bf16x8*)(ldsp + (bb) * 65536 + bRd + ks * 8192 + \
                                     (nh) * 512 + n2 * 256); \
  } while (0)

#define MFMA_Q(mh, nh, AF, BF) do { \
    _Pragma("unroll") for (int m4 = 0; m4 < 4; ++m4) \
    _Pragma("unroll") for (int n2 = 0; n2 < 2; ++n2) \
    _Pragma("unroll") for (int ks = 0; ks < 2; ++ks) \
      acc[(mh) * 4 + m4][(nh) * 2 + n2] = \
          __builtin_amdgcn_mfma_f32_16x16x32_bf16( \
              BF[n2][ks], AF[m4][ks], acc[(mh) * 4 + m4][(nh) * 2 + n2], 0, 0, 0); \
  } while (0)

#define TILE_BODY(bb, nb, tnext) do { \
    /* P1: stage tile t+1 (full, linear); read bY; MFMA (0,0) */ \
    PRE_LG(); \
    STAGE_ALL(nb, tnext); \
    READ_B(bY, bb, 1); \
    MFMA_Q(0, 0, aE, bZ); \
    POST(); \
    /* P2: read aO; MFMA (0,1) */ \
    PRE_LG(); \
    READ_A(aO, bb, 1); \
    MFMA_Q(0, 1, aE, bY); \
    POST(); \
    /* P3: vmcnt(0) (stage 2 phases old); read next aE; MFMA (1,0) */ \
    PRE_VM(); \
    READ_A(aE, nb, 0); \
    MFMA_Q(1, 0, aO, bZ); \
    POST(); \
    /* P4: read next bZ; MFMA (1,1) */ \
    PRE_LG(); \
    READ_B(bZ, nb, 0); \
    MFMA_Q(1, 1, aO, bY); \
    POST(); \
  } while (0)

  // ---- prologue ----
  STAGE_ALL(0, 0);
  asm volatile("s_waitcnt vmcnt(0)" ::: "memory");
  __builtin_amdgcn_sched_barrier(0);
  __builtin_amdgcn_s_barrier();
  __builtin_amdgcn_sched_barrier(0);
  READ_A(aE, 0, 0);
  READ_B(bZ, 0, 0);

  const int NP = NT >> 1;
  for (int j = 0; j < NP; ++j) {
    int t1 = 2 * j + 1;
    int t2 = 2 * j + 2; if (t2 > NT - 1) t2 = NT - 1;  // dummy last restage
    TILE_BODY(0, 1, t1);
    TILE_BODY(1, 0, t2);
  }
  asm volatile("s_waitcnt vmcnt(0) lgkmcnt(0)" ::: "memory");
  __builtin_amdgcn_sched_barrier(0);

  if constexpr (MODE == 1) {
    // ---- epilogue -> PACKED H (bf16, gelu): fully coalesced 256B blocks ----
    unsigned short* Hb = (unsigned short*)Cout + (size_t)e * cStride;
    unsigned short* Hw = Hb +
        ((size_t)(tm * (N >> 6) + tn * 4 + wn) * 2 + wm) * 8192 +
        (q >> 1) * 1024 + l15 * 8 + (q & 1) * 4;
#pragma unroll
    for (int nf = 0; nf < 4; ++nf) {
      int col = colTile + wn * 64 + nf * 16 + q * 4;
      float4 bv = *(const float4*)(bias + e * biasStride + col);
#pragma unroll
      for (int mf = 0; mf < 8; ++mf) {
        f32x4 v = acc[mf][nf];
        u16x4 o;
        o[0] = f2bf(gelu_f(v[0] + bv.x));
        o[1] = f2bf(gelu_f(v[1] + bv.y));
        o[2] = f2bf(gelu_f(v[2] + bv.z));
        o[3] = f2bf(gelu_f(v[3] + bv.w));
        *(u16x4*)(Hw + nf * 2048 + mf * 128) = o;
      }
    }
  } else {
    // ---- epilogue -> row-major fp32 Y via LDS repack (coalesced 64B/thr) ----
    __syncthreads();  // LDS free for reuse
    float* smf = (float*)ldsp;  // [32][260] fp32
    float* Yb = (float*)Cout + (size_t)e * cStride;
    const int srow = wm * 16 + l15;
    float4 bv[4];
#pragma unroll
    for (int nf = 0; nf < 4; ++nf)
      bv[nf] = *(const float4*)(bias + e * biasStride + colTile + wn * 64 +
                                nf * 16 + q * 4);
#pragma unroll
    for (int mf = 0; mf < 8; ++mf) {
#pragma unroll
      for (int nf = 0; nf < 4; ++nf) {
        f32x4 v = acc[mf][nf];
        f32x4 o = {v[0] + bv[nf].x, v[1] + bv[nf].y,
                   v[2] + bv[nf].z, v[3] + bv[nf].w};
        *(f32x4*)&smf[srow * 260 + wn * 64 + nf * 16 + q * 4] = o;
      }
      __syncthreads();
      {
        int r32 = tid >> 4, seg = tid & 15;
        int row = rowTile + (r32 >> 4) * 128 + mf * 16 + (r32 & 15);
        float* yr = Yb + (size_t)row * N + colTile + seg * 16;
        float4 v0 = *(float4*)&smf[r32 * 260 + seg * 16 + 0];
        float4 v1 = *(float4*)&smf[r32 * 260 + seg * 16 + 4];
        float4 v2 = *(float4*)&smf[r32 * 260 + seg * 16 + 8];
        float4 v3 = *(float4*)&smf[r32 * 260 + seg * 16 + 12];
        *(float4*)(yr + 0) = v0;
        *(float4*)(yr + 4) = v1;
        *(float4*)(yr + 8) = v2;
        *(float4*)(yr + 12) = v3;
      }
      __syncthreads();
    }
  }
}

extern "C" void kernel_launch(void* const* d_in, const int* in_sizes, int n_in,
                              void* d_out, int out_size, void* d_ws, size_t ws_size,
                              hipStream_t stream) {
  const float* X = (const float*)d_in[0];   // [1][E*C][D]
  const float* W1 = (const float*)d_in[1];  // [E][D][F]
  const float* b1 = (const float*)d_in[2];  // [E][F]
  const float* W2 = (const float*)d_in[3];  // [E][F][D]
  const float* b2 = (const float*)d_in[4];  // [E][D]
  float* Y = (float*)d_out;                 // [1][E*C][D]

  const size_t szX = (size_t)C_ * D_ * 2;
  const size_t szW1 = (size_t)F_ * D_ * 2;
  const size_t szW2 = (size_t)D_ * F_ * 2;
  const size_t szH = (size_t)C_ * F_ * 2;
  const size_t fixed = szX + szW1 + szW2;

  int g = 0;
  {
    const int cands[4] = {8, 4, 2, 1};
    for (int i = 0; i < 4; ++i)
      if ((fixed + szH) * (size_t)cands[i] <= ws_size) { g = cands[i]; break; }
  }
  int RC = C_;
  if (g == 0) {  // tiny-ws fallback: chunk rows (256-granular)
    g = 1;
    size_t avail = ws_size > fixed ? ws_size - fixed : 0;
    RC = (int)(avail / ((size_t)F_ * 2));
    RC = (RC / 256) * 256;
    if (RC < 256) RC = 256;
    if (RC > C_) RC = C_;
  }

  unsigned short* XP = (unsigned short*)d_ws;              // [g] packed X
  unsigned short* W1P = XP + (size_t)g * C_ * D_;          // [g] packed W1^T
  unsigned short* W2P = W1P + (size_t)g * F_ * D_;         // [g] packed W2^T
  unsigned short* HP = W2P + (size_t)g * D_ * F_;          // [g] packed H (RC rows)

  const int numN1 = F_ / 256;  // 16
  const int numN2 = D_ / 256;  // 4
  const int NT1 = D_ / 64;     // 16 (GEMM1 K-tiles)

  for (int e0 = 0; e0 < E_; e0 += g) {
    pack_rm_kernel<<<dim3(C_ / 256, D_ / 64, g), 256, 0, stream>>>(
        X + (size_t)e0 * C_ * D_, XP, C_, D_);
    pack_tr_kernel<<<dim3(F_ / 256, D_ / 64, g), 256, 0, stream>>>(
        W1 + (size_t)e0 * D_ * F_, W1P, D_, F_);
    pack_tr_kernel<<<dim3(D_ / 256, F_ / 64, g), 256, 0, stream>>>(
        W2 + (size_t)e0 * F_ * D_, W2P, F_, D_);

    for (int r0 = 0; r0 < C_; r0 += RC) {
      int numM = RC / 256;
      // GEMM1: H = gelu(X @ W1 + b1) -> packed H, [RC x F], K = D
      gemm256_kernel<1><<<dim3((unsigned)(numM * numN1 * g)), 512, 0, stream>>>(
          XP + (size_t)(r0 >> 8) * NT1 * 16384, W1P, b1 + (size_t)e0 * F_,
          (void*)HP, D_, F_, numM, numN1,
          (size_t)C_ * D_, (size_t)F_ * D_, (size_t)RC * F_, F_);
      // GEMM2: Y = H @ W2 + b2, [RC x D], K = F
      gemm256_kernel<0><<<dim3((unsigned)(numM * numN2 * g)), 512, 0, stream>>>(
          HP, W2P, b2 + (size_t)e0 * D_,
          (void*)(Y + (size_t)e0 * C_ * D_ + (size_t)r0 * D_),
          F_, D_, numM, numN2,
          (size_t)RC * F_, (size_t)D_ * F_, (size_t)C_ * D_, D_);
    }
  }
}

// Round 7
// 815.424 us; speedup vs baseline: 1.0554x; 1.0554x over previous
//
#include <hip/hip_runtime.h>
#include <stdint.h>

// Experts FFN: E experts, C tokens/expert, D model, F ff
#define E_ 8
#define C_ 4096
#define D_ 1024
#define F_ 4096

typedef __attribute__((ext_vector_type(8))) short bf16x8;
typedef __attribute__((ext_vector_type(4))) float f32x4;
typedef __attribute__((ext_vector_type(8))) unsigned short u16x8;
typedef __attribute__((ext_vector_type(4))) unsigned short u16x4;

__device__ __forceinline__ unsigned short f2bf(float x) {
  union { float f; uint32_t u; } v; v.f = x;
  uint32_t r = v.u + 0x7FFFu + ((v.u >> 16) & 1u);  // RNE
  return (unsigned short)(r >> 16);
}

// JAX gelu (approximate=True)
__device__ __forceinline__ float gelu_f(float x) {
  float x3 = x * x * x;
  float u = 0.7978845608028654f * __builtin_fmaf(0.044715f, x3, x);
  float t = __expf(2.0f * u);
  float th = 1.0f - 2.0f / (t + 1.0f);
  return 0.5f * x * (1.0f + th);
}

// ---------------- elementwise fp32 -> bf16 ----------------
__global__ void convert_bf16_kernel(const float* __restrict__ in,
                                    unsigned short* __restrict__ out, size_t n) {
  size_t i = ((size_t)blockIdx.x * blockDim.x + threadIdx.x) * 8;
  size_t stride = (size_t)gridDim.x * blockDim.x * 8;
  for (; i < n; i += stride) {
    float4 a = *(const float4*)(in + i);
    float4 b = *(const float4*)(in + i + 4);
    u16x8 o;
    o[0] = f2bf(a.x); o[1] = f2bf(a.y); o[2] = f2bf(a.z); o[3] = f2bf(a.w);
    o[4] = f2bf(b.x); o[5] = f2bf(b.y); o[6] = f2bf(b.z); o[7] = f2bf(b.w);
    *(u16x8*)(out + i) = o;
  }
}

// ---------------- tiled transpose: fp32 [K][N] -> bf16 [N][K] ----------------
__global__ void transpose_bf16_kernel(const float* __restrict__ in,
                                      unsigned short* __restrict__ out,
                                      int K, int N) {
  const int ge = blockIdx.z;
  const float* src = in + (size_t)ge * K * N;
  unsigned short* dst = out + (size_t)ge * K * N;
  __shared__ float tile[32][33];
  int t = threadIdx.x;
  int tx = t & 31, ty = t >> 5;  // 32 x 8
  int k0 = blockIdx.x * 32, n0 = blockIdx.y * 32;
#pragma unroll
  for (int p = 0; p < 4; ++p)
    tile[ty + p * 8][tx] = src[(size_t)(k0 + ty + p * 8) * N + n0 + tx];
  __syncthreads();
#pragma unroll
  for (int p = 0; p < 4; ++p)
    dst[(size_t)(n0 + ty + p * 8) * K + k0 + tx] = f2bf(tile[tx][ty + p * 8]);
}

// ---------------- async global->LDS ----------------
typedef const __attribute__((address_space(1))) uint32_t* gas1_ptr;
typedef __attribute__((address_space(3))) uint32_t* las3_ptr;

__device__ __forceinline__ void async16(const void* g, void* l) {
  __builtin_amdgcn_global_load_lds((gas1_ptr)(uintptr_t)g, (las3_ptr)(uintptr_t)l,
                                   16, 0, 0);
}

// ============================================================================
// 256x256 8-phase bf16 GEMM, R4 schedule + EXPLICIT INTERLEAVE PINNING:
// every phase cluster is emitted as [2 MFMA | fence | mem-unit | fence] x 8,
// preventing the compiler from sinking next-phase ds_reads / global_load_lds
// issues below the MFMA block (which serialized all prior rounds to the
// 2-phase baseline). Schedule, vm-ledger (2/4/4/2), staging positions, LDS
// layout, and epilogue are IDENTICAL to R4 (verified correct).
// ============================================================================

#define FEN() __builtin_amdgcn_sched_barrier(0)

#define PRE(VM) do { \
    __builtin_amdgcn_sched_barrier(0); \
    asm volatile("s_waitcnt vmcnt(" #VM ")" ::: "memory"); \
    __builtin_amdgcn_s_barrier(); \
    asm volatile("s_waitcnt lgkmcnt(0)" ::: "memory"); \
    __builtin_amdgcn_sched_barrier(0); \
    __builtin_amdgcn_s_setprio(1); \
  } while (0)

#define POST() do { \
    __builtin_amdgcn_s_setprio(0); \
    __builtin_amdgcn_sched_barrier(0); \
    __builtin_amdgcn_s_barrier(); \
    __builtin_amdgcn_sched_barrier(0); \
  } while (0)

template <int MODE>
__global__ __launch_bounds__(512, 2) void gemm256_kernel(
    const unsigned short* __restrict__ A,  // [M][K] bf16
    const unsigned short* __restrict__ B,  // [N][K] bf16
    const float* __restrict__ bias,        // [N]
    void* __restrict__ Cout,
    int K, int N, int numM, int numN,
    size_t aStride, size_t bStride, size_t cStride, int biasStride) {
  __shared__ char lds[131072];
  char* ldsp = (char*)lds;

  const int NT = K >> 6;
  const int NITER = NT >> 1;

  // bijective XCD swizzle (m204)
  int lin = blockIdx.x;
  int nwg = gridDim.x;
  int qq = nwg >> 3, rr8 = nwg & 7;
  int xcd = lin & 7, idx = lin >> 3;
  int wg = (xcd < rr8 ? xcd * (qq + 1) : rr8 * (qq + 1) + (xcd - rr8) * qq) + idx;
  int per = numM * numN;
  int e = wg / per;
  int rem = wg - e * per;
  int tm = rem % numM, tn = rem / numM;

  A += (size_t)e * aStride;
  B += (size_t)e * bStride;
  bias += (size_t)e * biasStride;

  const int rowTile = tm << 8;
  const int colTile = tn << 8;

  const int tid = threadIdx.x;
  const int lane = tid & 63;
  const int w = tid >> 6;
  const int wm = w & 1, wn = w >> 1;
  const int l15 = lane & 15, q = lane >> 4;

  const size_t ldB = (size_t)K * 2;

  // ---- staging: per-lane voffsets + uniform scalar bases ----
  const int rlo = tid >> 3, kc = tid & 7;
  const int swzsrc = ((kc ^ (rlo & 7)) << 4);
  const int vA = (int)(rlo * (int)ldB) + swzsrc;
  const int bcol = (rlo & 31) + ((rlo >> 5) << 6);
  const int vB = (int)(bcol * (int)ldB) + swzsrc;
  const int dA = tid * 16;
  const int dB = 32768 + (rlo & 31) * 128 + (rlo >> 5) * 8192 + kc * 16;
  const char* Ag = (const char*)A + (size_t)rowTile * ldB;
  const char* Bg = (const char*)B + (size_t)colTile * ldB;
  const size_t r128 = (size_t)128 * ldB;

#define STAGE_A(bb, Ah, kt) do { \
    size_t u = (size_t)((Ah) * 64) * ldB + (size_t)(kt) * 128; \
    async16(Ag + u + vA, ldsp + (bb) * 65536 + (Ah) * 8192 + dA); \
    async16(Ag + u + r128 + vA, \
            ldsp + (bb) * 65536 + (Ah) * 8192 + 16384 + dA); \
  } while (0)

#define STAGE_B(bb, Bh, kt) do { \
    size_t u = (size_t)((Bh) * 32) * ldB + (size_t)(kt) * 128; \
    async16(Bg + u + vB, ldsp + (bb) * 65536 + (Bh) * 4096 + dB); \
    async16(Bg + u + r128 + vB, \
            ldsp + (bb) * 65536 + (Bh) * 4096 + 16384 + dB); \
  } while (0)

  // ---- LDS read base offsets (buf x ks variants) ----
  const int k0 = (q * 16) ^ ((l15 & 7) << 4);
  const int iA00 = wm * 16384 + l15 * 128 + k0;
  const int iA01 = iA00 ^ 64;
  const int iA10 = iA00 + 65536;
  const int iA11 = iA01 + 65536;
  const int iB00 = 32768 + wn * 8192 + l15 * 128 + k0;
  const int iB01 = iB00 ^ 64;
  const int iB10 = iB00 + 65536;
  const int iB11 = iB01 + 65536;

  bf16x8 aE[4][2], aO[4][2], bZ[2][2], bY[2][2];
  f32x4 acc[8][4];
#pragma unroll
  for (int m = 0; m < 8; ++m)
#pragma unroll
    for (int n = 0; n < 4; ++n) acc[m][n] = {0.f, 0.f, 0.f, 0.f};

  // one dependent MFMA pair (ks=0,1) for quadrant (mh,nh), frag (m4,n2)
#define PR(mh, nh, AF, BF, m4, n2) do { \
    acc[(mh)*4+(m4)][(nh)*2+(n2)] = __builtin_amdgcn_mfma_f32_16x16x32_bf16( \
        BF[n2][0], AF[m4][0], acc[(mh)*4+(m4)][(nh)*2+(n2)], 0, 0, 0); \
    acc[(mh)*4+(m4)][(nh)*2+(n2)] = __builtin_amdgcn_mfma_f32_16x16x32_bf16( \
        BF[n2][1], AF[m4][1], acc[(mh)*4+(m4)][(nh)*2+(n2)], 0, 0, 0); \
  } while (0)

  // 2 ds_read_b128 (ks=0,1) of one A-frag / one B-frag
#define RA(dst, b0, b1, mh, m4) do { \
    dst[m4][0] = *(const bf16x8*)(ldsp + (b0) + (mh) * 8192 + (m4) * 2048); \
    dst[m4][1] = *(const bf16x8*)(ldsp + (b1) + (mh) * 8192 + (m4) * 2048); \
  } while (0)

#define RB(dst, b0, b1, nh, n2) do { \
    dst[n2][0] = *(const bf16x8*)(ldsp + (b0) + (nh) * 4096 + (n2) * 2048); \
    dst[n2][1] = *(const bf16x8*)(ldsp + (b1) + (nh) * 4096 + (n2) * 2048); \
  } while (0)

  // ---- interleaved phase bodies (R4 schedule, order-pinned) ----
#define PH_Q00(AF, BF, BYd, cB0, cB1, sb, st) do { \
    PRE(2); \
    PR(0,0,AF,BF,0,0); FEN(); STAGE_A(sb,0,st); FEN(); \
    PR(0,0,AF,BF,0,1); FEN(); STAGE_B(sb,0,st); FEN(); \
    PR(0,0,AF,BF,1,0); FEN(); RB(BYd,cB0,cB1,1,0); FEN(); \
    PR(0,0,AF,BF,1,1); FEN(); RB(BYd,cB0,cB1,1,1); FEN(); \
    PR(0,0,AF,BF,2,0); PR(0,0,AF,BF,2,1); \
    PR(0,0,AF,BF,3,0); PR(0,0,AF,BF,3,1); \
    POST(); \
  } while (0)

#define PH_Q01(AF, BF, AOd, cA0, cA1) do { \
    PRE(4); \
    PR(0,1,AF,BF,0,0); FEN(); RA(AOd,cA0,cA1,1,0); FEN(); \
    PR(0,1,AF,BF,0,1); FEN(); RA(AOd,cA0,cA1,1,1); FEN(); \
    PR(0,1,AF,BF,1,0); FEN(); RA(AOd,cA0,cA1,1,2); FEN(); \
    PR(0,1,AF,BF,1,1); FEN(); RA(AOd,cA0,cA1,1,3); FEN(); \
    PR(0,1,AF,BF,2,0); PR(0,1,AF,BF,2,1); \
    PR(0,1,AF,BF,3,0); PR(0,1,AF,BF,3,1); \
    POST(); \
  } while (0)

#define PH_Q10(AF, BF, sb, st) do { \
    PRE(4); \
    PR(1,0,AF,BF,0,0); FEN(); STAGE_B(sb,1,st); FEN(); \
    PR(1,0,AF,BF,0,1); PR(1,0,AF,BF,1,0); PR(1,0,AF,BF,1,1); \
    PR(1,0,AF,BF,2,0); PR(1,0,AF,BF,2,1); \
    PR(1,0,AF,BF,3,0); PR(1,0,AF,BF,3,1); \
    POST(); \
  } while (0)

#define PH_Q11(AF, BF, AEd, BZd, nA0, nA1, nB0, nB1, sb, st) do { \
    PRE(2); \
    PR(1,1,AF,BF,0,0); FEN(); STAGE_A(sb,1,st); FEN(); \
    PR(1,1,AF,BF,0,1); FEN(); RA(AEd,nA0,nA1,0,0); FEN(); \
    PR(1,1,AF,BF,1,0); FEN(); RA(AEd,nA0,nA1,0,1); FEN(); \
    PR(1,1,AF,BF,1,1); FEN(); RA(AEd,nA0,nA1,0,2); FEN(); \
    PR(1,1,AF,BF,2,0); FEN(); RA(AEd,nA0,nA1,0,3); FEN(); \
    PR(1,1,AF,BF,2,1); FEN(); RB(BZd,nB0,nB1,0,0); FEN(); \
    PR(1,1,AF,BF,3,0); FEN(); RB(BZd,nB0,nB1,0,1); FEN(); \
    PR(1,1,AF,BF,3,1); \
    POST(); \
  } while (0)

  // ---- prologue: tile0 -> buf0 only; tile1 staged inside loop ----
  STAGE_A(0, 0, 0); STAGE_B(0, 0, 0); STAGE_B(0, 1, 0); STAGE_A(0, 1, 0);
  asm volatile("s_waitcnt vmcnt(0)" ::: "memory");
  __builtin_amdgcn_sched_barrier(0);
  __builtin_amdgcn_s_barrier();
  __builtin_amdgcn_sched_barrier(0);
  RA(aE, iA00, iA01, 0, 0); RA(aE, iA00, iA01, 0, 1);
  RA(aE, iA00, iA01, 0, 2); RA(aE, iA00, iA01, 0, 3);
  RB(bZ, iB00, iB01, 0, 0); RB(bZ, iB00, iB01, 0, 1);

  for (int j = 0; j < NITER; ++j) {
    int t1 = 2 * j + 1;
    int t2 = 2 * j + 2; if (t2 > NT - 1) t2 = NT - 1;  // dummy last restage
    // tile 2j on buf0; stage t1 -> buf1
    PH_Q00(aE, bZ, bY, iB00, iB01, 1, t1);
    PH_Q01(aE, bY, aO, iA00, iA01);
    PH_Q10(aO, bZ, 1, t1);
    PH_Q11(aO, bY, aE, bZ, iA10, iA11, iB10, iB11, 1, t1);
    // tile 2j+1 on buf1; stage t2 -> buf0
    PH_Q00(aE, bZ, bY, iB10, iB11, 0, t2);
    PH_Q01(aE, bY, aO, iA10, iA11);
    PH_Q10(aO, bZ, 0, t2);
    PH_Q11(aO, bY, aE, bZ, iA00, iA01, iB00, iB01, 0, t2);
  }
  asm volatile("s_waitcnt vmcnt(0) lgkmcnt(0)" ::: "memory");
  __builtin_amdgcn_sched_barrier(0);

  // ---- epilogue: swapped layout => lane l15 = row, q*4+j = col ----
#pragma unroll
  for (int mf = 0; mf < 8; ++mf) {
    int row = rowTile + wm * 128 + mf * 16 + l15;
#pragma unroll
    for (int nf = 0; nf < 4; ++nf) {
      int col = colTile + wn * 64 + nf * 16 + q * 4;
      float4 bv = *(const float4*)(bias + col);
      f32x4 v = acc[mf][nf];
      if constexpr (MODE == 1) {
        u16x4 o;
        o[0] = f2bf(gelu_f(v[0] + bv.x));
        o[1] = f2bf(gelu_f(v[1] + bv.y));
        o[2] = f2bf(gelu_f(v[2] + bv.z));
        o[3] = f2bf(gelu_f(v[3] + bv.w));
        *(u16x4*)((unsigned short*)Cout + (size_t)e * cStride +
                  (size_t)row * N + col) = o;
      } else {
        float4 o;
        o.x = v[0] + bv.x; o.y = v[1] + bv.y;
        o.z = v[2] + bv.z; o.w = v[3] + bv.w;
        *(float4*)((float*)Cout + (size_t)e * cStride + (size_t)row * N + col) = o;
      }
    }
  }
}

extern "C" void kernel_launch(void* const* d_in, const int* in_sizes, int n_in,
                              void* d_out, int out_size, void* d_ws, size_t ws_size,
                              hipStream_t stream) {
  const float* X = (const float*)d_in[0];   // [1][E*C][D]
  const float* W1 = (const float*)d_in[1];  // [E][D][F]
  const float* b1 = (const float*)d_in[2];  // [E][F]
  const float* W2 = (const float*)d_in[3];  // [E][F][D]
  const float* b2 = (const float*)d_in[4];  // [E][D]
  float* Y = (float*)d_out;                 // [1][E*C][D]

  const size_t szX = (size_t)C_ * D_ * 2;
  const size_t szW1 = (size_t)F_ * D_ * 2;
  const size_t szW2 = (size_t)D_ * F_ * 2;
  const size_t szH = (size_t)C_ * F_ * 2;
  const size_t fixed = szX + szW1 + szW2;

  int g = 0;
  {
    const int cands[4] = {8, 4, 2, 1};
    for (int i = 0; i < 4; ++i)
      if ((fixed + szH) * (size_t)cands[i] <= ws_size) { g = cands[i]; break; }
  }
  int RC = C_;
  if (g == 0) {  // tiny-ws fallback: chunk rows (256-granular for BM=256)
    g = 1;
    size_t avail = ws_size > fixed ? ws_size - fixed : 0;
    RC = (int)(avail / ((size_t)F_ * 2));
    RC = (RC / 256) * 256;
    if (RC < 256) RC = 256;
    if (RC > C_) RC = C_;
  }

  unsigned short* XB = (unsigned short*)d_ws;              // [g][C][D]
  unsigned short* W1T = XB + (size_t)g * C_ * D_;          // [g][F][D]
  unsigned short* W2T = W1T + (size_t)g * F_ * D_;         // [g][D][F]
  unsigned short* H = W2T + (size_t)g * D_ * F_;           // [g][RC][F]

  const int numN1 = F_ / 256;  // 16
  const int numN2 = D_ / 256;  // 4

  for (int e0 = 0; e0 < E_; e0 += g) {
    {
      size_t n = (size_t)g * C_ * D_;
      size_t nb = (n / 8 + 255) / 256;
      if (nb > 2048) nb = 2048;
      convert_bf16_kernel<<<dim3((unsigned)nb), 256, 0, stream>>>(
          X + (size_t)e0 * C_ * D_, XB, n);
    }
    transpose_bf16_kernel<<<dim3(D_ / 32, F_ / 32, g), 256, 0, stream>>>(
        W1 + (size_t)e0 * D_ * F_, W1T, D_, F_);
    transpose_bf16_kernel<<<dim3(F_ / 32, D_ / 32, g), 256, 0, stream>>>(
        W2 + (size_t)e0 * F_ * D_, W2T, F_, D_);

    for (int r0 = 0; r0 < C_; r0 += RC) {
      int numM = RC / 256;
      // GEMM1: H = gelu(XB @ W1T^T + b1), [RC x F], K = D
      gemm256_kernel<1><<<dim3((unsigned)(numM * numN1 * g)), 512, 0, stream>>>(
          XB + (size_t)r0 * D_, W1T, b1 + (size_t)e0 * F_, (void*)H,
          D_, F_, numM, numN1,
          (size_t)C_ * D_, (size_t)F_ * D_, (size_t)RC * F_, F_);
      // GEMM2: Y = H @ W2T^T + b2, [RC x D], K = F
      gemm256_kernel<0><<<dim3((unsigned)(numM * numN2 * g)), 512, 0, stream>>>(
          H, W2T, b2 + (size_t)e0 * D_,
          (void*)(Y + (size_t)e0 * C_ * D_ + (size_t)r0 * D_),
          F_, D_, numM, numN2,
          (size_t)RC * F_, (size_t)D_ * F_, (size_t)C_ * D_, D_);
    }
  }
}